// Round 5
// baseline (204.554 us; speedup 1.0000x reference)
//
#include <hip/hip_runtime.h>
#include <hip/hip_bf16.h>

#define L_  512
#define B_  4
#define E_  256
#define TT  16
#define TI  32

typedef unsigned short u16;
#define NLOG2E (-1.44269504f)

__device__ __forceinline__ float bflo(unsigned u) { return __uint_as_float(u << 16); }
__device__ __forceinline__ float bfhi(unsigned u) { return __uint_as_float(u & 0xffff0000u); }

__device__ __forceinline__ unsigned pack_bf2(float x, float y) {
  __hip_bfloat162 h = __float22bfloat162_rn(make_float2(x, y));
  return *reinterpret_cast<unsigned*>(&h);
}

// inputs pre-scaled by -log2(e):  sig(x) = 1/(1+2^(xs)) = sigmoid(original x)
__device__ __forceinline__ float sigs(float xs) {
  float e = __builtin_amdgcn_exp2f(xs);
  return __builtin_amdgcn_rcpf(1.0f + e);
}

// ---------------- prescan: CE = cumsum_l(emb), also zero-init out.
// 128 blocks x 256 thr; block owns 8 of the 1024 (b,e) columns.
__global__ __launch_bounds__(256) void prescan_k(
    const float* __restrict__ emb, float* __restrict__ CE, float* __restrict__ out0) {
  const int bc = blockIdx.x;
  const int cg = threadIdx.x & 1;        // 2 float4 col groups
  const int rk = threadIdx.x >> 1;       // 0..127 -> rows rk*4..rk*4+3
  const int col = bc * 8 + cg * 4;
  __shared__ float4 s_p[128][2];
  float4 part = {0.f, 0.f, 0.f, 0.f};
  for (int l = rk * 4; l < rk * 4 + 4; ++l) {
    float4 v = *(const float4*)(emb + (size_t)l * 1024 + col);
    part.x += v.x; part.y += v.y; part.z += v.z; part.w += v.w;
  }
  s_p[rk][cg] = part;
  __syncthreads();
  float4 run = {0.f, 0.f, 0.f, 0.f};
  for (int k = 0; k < rk; ++k) {
    float4 p = s_p[k][cg];
    run.x += p.x; run.y += p.y; run.z += p.z; run.w += p.w;
  }
  for (int l = rk * 4; l < rk * 4 + 4; ++l) {
    size_t o = (size_t)l * 1024 + col;
    float4 v = *(const float4*)(emb + o);
    run.x += v.x; run.y += v.y; run.z += v.z; run.w += v.w;
    *(float4*)(CE + o) = run;
  }
  // zero-init out: 524288 floats / 32768 threads = 16 floats each
  const float4 z = {0.f, 0.f, 0.f, 0.f};
  float* op = out0 + ((size_t)bc * 256 + threadIdx.x) * 16;
#pragma unroll
  for (int j = 0; j < 4; ++j) *(float4*)(op + j * 4) = z;
}

// ---------------- gemm: bx<128 -> U = NLOG2E*(emb.w1^T)  (BM=64, K=256)
//                  bx>=128 -> QC = NLOG2E*(emb.w2^T + CE.w3^T + b3) (BM=32, K=512)
__global__ __launch_bounds__(256) void gemm_k(
    const float* __restrict__ emb, const float* __restrict__ CE,
    const float* __restrict__ w1, const float* __restrict__ w2, const float* __restrict__ w3,
    const float* __restrict__ b3, float* __restrict__ U, float* __restrict__ QC) {
  __shared__ float As[64 * 32], Ws[64 * 32];
  const int tid = threadIdx.x, tx = tid & 15, ty = tid >> 4;
  const int bx = blockIdx.x;
  if (bx < 128) {
    const int r0 = (bx >> 2) * 64, f0 = (bx & 3) * 64;
    float acc[4][4] = {};
    for (int kb = 0; kb < 256; kb += 32) {
      for (int j = 0; j < 2; ++j) {
        int idx = j * 256 + tid;
        int r = idx >> 3, g = idx & 7;
        int gs = g ^ ((r >> 2) & 7);
        *(float4*)(As + r * 32 + gs * 4) = *(const float4*)(emb + (size_t)(r0 + r) * E_ + kb + g * 4);
        *(float4*)(Ws + r * 32 + gs * 4) = *(const float4*)(w1 + (size_t)(f0 + r) * E_ + kb + g * 4);
      }
      __syncthreads();
#pragma unroll
      for (int g = 0; g < 8; ++g) {
        float4 a[4], w[4];
#pragma unroll
        for (int i = 0; i < 4; ++i) {
          int r = ty * 4 + i;
          a[i] = *(const float4*)(As + r * 32 + (g ^ ((r >> 2) & 7)) * 4);
          int f = tx * 4 + i;
          w[i] = *(const float4*)(Ws + f * 32 + (g ^ ((f >> 2) & 7)) * 4);
        }
#pragma unroll
        for (int i = 0; i < 4; ++i)
#pragma unroll
          for (int j = 0; j < 4; ++j)
            acc[i][j] += a[i].x * w[j].x + a[i].y * w[j].y + a[i].z * w[j].z + a[i].w * w[j].w;
      }
      __syncthreads();
    }
#pragma unroll
    for (int i = 0; i < 4; ++i) {
      float4 v = make_float4(acc[i][0] * NLOG2E, acc[i][1] * NLOG2E,
                             acc[i][2] * NLOG2E, acc[i][3] * NLOG2E);
      *(float4*)(U + (size_t)(r0 + ty * 4 + i) * E_ + f0 + tx * 4) = v;
    }
  } else {
    const int y = bx - 128;
    const int r0 = (y >> 2) * 32, f0 = (y & 3) * 64;
    float acc[2][4] = {};
    for (int kb16 = 0; kb16 < 16; ++kb16) {
      const float* A = (kb16 < 8) ? emb : CE;
      const float* W = (kb16 < 8) ? w2 : w3;
      const int kk = (kb16 & 7) * 32;
      {
        int r = tid >> 3, g = tid & 7;
        int gs = g ^ ((r >> 2) & 7);
        *(float4*)(As + r * 32 + gs * 4) = *(const float4*)(A + (size_t)(r0 + r) * E_ + kk + g * 4);
      }
      for (int j = 0; j < 2; ++j) {
        int idx = j * 256 + tid;
        int fr = idx >> 3, g = idx & 7;
        int gs = g ^ ((fr >> 2) & 7);
        *(float4*)(Ws + fr * 32 + gs * 4) = *(const float4*)(W + (size_t)(f0 + fr) * E_ + kk + g * 4);
      }
      __syncthreads();
#pragma unroll
      for (int g = 0; g < 8; ++g) {
        float4 a[2], w[4];
#pragma unroll
        for (int i = 0; i < 2; ++i) {
          int r = ty * 2 + i;
          a[i] = *(const float4*)(As + r * 32 + (g ^ ((r >> 2) & 7)) * 4);
        }
#pragma unroll
        for (int j = 0; j < 4; ++j) {
          int f = tx * 4 + j;
          w[j] = *(const float4*)(Ws + f * 32 + (g ^ ((f >> 2) & 7)) * 4);
        }
#pragma unroll
        for (int i = 0; i < 2; ++i)
#pragma unroll
          for (int j = 0; j < 4; ++j)
            acc[i][j] += a[i].x * w[j].x + a[i].y * w[j].y + a[i].z * w[j].z + a[i].w * w[j].w;
      }
      __syncthreads();
    }
    float4 bb = *(const float4*)(b3 + f0 + tx * 4);
#pragma unroll
    for (int i = 0; i < 2; ++i) {
      float4 v = make_float4(NLOG2E * (acc[i][0] + bb.x), NLOG2E * (acc[i][1] + bb.y),
                             NLOG2E * (acc[i][2] + bb.z), NLOG2E * (acc[i][3] + bb.w));
      *(float4*)(QC + (size_t)(r0 + ty * 2 + i) * E_ + f0 + tx * 4) = v;
    }
  }
}

// ---------------- main: gate + PV for (t-tile of 16, i-chunk of 32, b); 512 threads
__global__ __launch_bounds__(512, 8) void attn_main_k(
    const float* __restrict__ emb, const float* __restrict__ U,
    const float* __restrict__ QC, const float* __restrict__ w0g,
    float* __restrict__ out) {
  const int t0 = blockIdx.x * TT, i0 = blockIdx.y * TI, b = blockIdx.z;
  if (i0 > t0) return;  // i0,t0 grid-aligned: i0>t0 => i0 >= t0+16 > all t in tile

  __shared__ u16 tile[TI * 264];
  __shared__ float s_s[TT][TI];
  const int tid = threadIdx.x, wave = tid >> 6, lane = tid & 63;
  const int il = lane & 31, eh = lane >> 5;

  // stage U rows i0..i0+31 (bf16, pre-scaled by -log2e): 8 waves x 4 rows
  {
    const float* src = U + ((size_t)i0 * B_ + b) * E_ + lane * 4;
#pragma unroll
    for (int c = 0; c < 4; ++c) {
      int r = c * 8 + wave;
      float4 v = *(const float4*)(src + (size_t)r * (B_ * E_));
      *(uint2*)(tile + r * 264 + lane * 4) =
          make_uint2(pack_bf2(v.x, v.y), pack_bf2(v.z, v.w));
    }
  }
  __syncthreads();

  // gate: lane handles (t = t0 + wave*2 + eh, i = i0 + il), full e-sweep
  {
    const int t = t0 + wave * 2 + eh;
    const float* qrow = QC + ((size_t)t * B_ + b) * E_;  // half-wave-uniform -> broadcast loads
    const u16* urow = tile + il * 264;
    float a0 = 0.f, a1 = 0.f, a2 = 0.f, a3 = 0.f;
#pragma unroll 4
    for (int g = 0; g < 32; ++g) {
      uint4 raw = *(const uint4*)(urow + g * 8);
      float4 q0 = *(const float4*)(qrow + g * 8);
      float4 q1 = *(const float4*)(qrow + g * 8 + 4);
      float4 z0 = *(const float4*)(w0g + g * 8);
      float4 z1 = *(const float4*)(w0g + g * 8 + 4);
      a0 += z0.x * sigs(bflo(raw.x) + q0.x); a1 += z0.y * sigs(bfhi(raw.x) + q0.y);
      a2 += z0.z * sigs(bflo(raw.y) + q0.z); a3 += z0.w * sigs(bfhi(raw.y) + q0.w);
      a0 += z1.x * sigs(bflo(raw.z) + q1.x); a1 += z1.y * sigs(bfhi(raw.z) + q1.y);
      a2 += z1.z * sigs(bflo(raw.w) + q1.z); a3 += z1.w * sigs(bfhi(raw.w) + q1.w);
    }
    float s = (a0 + a1) + (a2 + a3);
    if (i0 + il > t) s = 0.f;
    s_s[0][wave * 64 + lane] = s;   // == s_s[wave*2+eh][il], linear store
  }
  __syncthreads();

  // PV: per wave 2 t's; lanes own e (4 floats); emb direct from global (L1 broadcast)
  {
    const int tA = t0 + wave * 2, tB = tA + 1;
    const float* embp = emb + ((size_t)i0 * B_ + b) * E_ + lane * 4;
    const float* sAv = s_s[wave * 2];
    const float* sBv = s_s[wave * 2 + 1];
    int nI = min(TI, tB - i0 + 1);
    nI = (nI + 3) & ~3;
    float4 o0 = {0.f, 0.f, 0.f, 0.f}, o1 = {0.f, 0.f, 0.f, 0.f};
    for (int i = 0; i < nI; i += 4) {
#pragma unroll
      for (int k2 = 0; k2 < 4; ++k2) {
        float4 r = *(const float4*)(embp + (size_t)(i + k2) * (B_ * E_));
        float sa = sAv[i + k2], sb = sBv[i + k2];
        o0.x += sa * r.x; o0.y += sa * r.y; o0.z += sa * r.z; o0.w += sa * r.w;
        o1.x += sb * r.x; o1.y += sb * r.y; o1.z += sb * r.z; o1.w += sb * r.w;
      }
    }
    float* opA = out + ((size_t)tA * B_ + b) * E_ + lane * 4;
    float* opB = out + ((size_t)tB * B_ + b) * E_ + lane * 4;
    atomicAdd(opA + 0, o0.x); atomicAdd(opA + 1, o0.y);
    atomicAdd(opA + 2, o0.z); atomicAdd(opA + 3, o0.w);
    atomicAdd(opB + 0, o1.x); atomicAdd(opB + 1, o1.y);
    atomicAdd(opB + 2, o1.z); atomicAdd(opB + 3, o1.w);
  }
}

extern "C" void kernel_launch(void* const* d_in, const int* in_sizes, int n_in,
                              void* d_out, int out_size, void* d_ws, size_t ws_size,
                              hipStream_t stream) {
  const float* emb = (const float*)d_in[0];
  const float* w1  = (const float*)d_in[1];
  const float* w2  = (const float*)d_in[2];
  const float* w3  = (const float*)d_in[3];
  const float* b3  = (const float*)d_in[4];
  const float* w0  = (const float*)d_in[5];
  float* out = (float*)d_out;

  float* CE = (float*)d_ws;            // 2048x256 cumsum(emb)
  float* U  = CE + 524288;             // 2048x256, pre-scaled by -log2e
  float* QC = U + 524288;              // 2048x256, NLOG2E*(q2+c3+b3)

  prescan_k<<<dim3(128), 256, 0, stream>>>(emb, CE, out);
  gemm_k<<<dim3(384), 256, 0, stream>>>(emb, CE, w1, w2, w3, b3, U, QC);
  attn_main_k<<<dim3(L_ / TT, L_ / TI, B_), 512, 0, stream>>>(emb, U, QC, w0, out);
}

// Round 7
// 173.095 us; speedup vs baseline: 1.1817x; 1.1817x over previous
//
#include <hip/hip_runtime.h>
#include <hip/hip_bf16.h>

#define L_  512
#define B_  4
#define E_  256
#define TT  16
#define TI  64

typedef unsigned short u16;
#define NLOG2E (-1.44269504f)

__device__ __forceinline__ float bflo(unsigned u) { return __uint_as_float(u << 16); }
__device__ __forceinline__ float bfhi(unsigned u) { return __uint_as_float(u & 0xffff0000u); }

__device__ __forceinline__ unsigned pack_bf2(float x, float y) {
  __hip_bfloat162 h = __float22bfloat162_rn(make_float2(x, y));
  return *reinterpret_cast<unsigned*>(&h);
}

// inputs pre-scaled by -log2(e):  sig(x) = 1/(1+2^(xs)) = sigmoid(original x)
__device__ __forceinline__ float sigs(float xs) {
  float e = __builtin_amdgcn_exp2f(xs);
  return __builtin_amdgcn_rcpf(1.0f + e);
}

// ---------------- prescan: CE = cumsum_l(emb), also zero-init out.
// 128 blocks x 256 thr; block owns 8 of the 1024 (b,e) columns.
__global__ __launch_bounds__(256) void prescan_k(
    const float* __restrict__ emb, float* __restrict__ CE, float* __restrict__ out0) {
  const int bc = blockIdx.x;
  const int cg = threadIdx.x & 1;        // 2 float4 col groups
  const int rk = threadIdx.x >> 1;       // 0..127 -> rows rk*4..rk*4+3
  const int col = bc * 8 + cg * 4;
  __shared__ float4 s_p[128][2];
  float4 part = {0.f, 0.f, 0.f, 0.f};
  for (int l = rk * 4; l < rk * 4 + 4; ++l) {
    float4 v = *(const float4*)(emb + (size_t)l * 1024 + col);
    part.x += v.x; part.y += v.y; part.z += v.z; part.w += v.w;
  }
  s_p[rk][cg] = part;
  __syncthreads();
  float4 run = {0.f, 0.f, 0.f, 0.f};
  for (int k = 0; k < rk; ++k) {
    float4 p = s_p[k][cg];
    run.x += p.x; run.y += p.y; run.z += p.z; run.w += p.w;
  }
  for (int l = rk * 4; l < rk * 4 + 4; ++l) {
    size_t o = (size_t)l * 1024 + col;
    float4 v = *(const float4*)(emb + o);
    run.x += v.x; run.y += v.y; run.z += v.z; run.w += v.w;
    *(float4*)(CE + o) = run;
  }
  // zero-init out: 524288 floats / 32768 threads = 16 floats each
  const float4 z = {0.f, 0.f, 0.f, 0.f};
  float* op = out0 + ((size_t)bc * 256 + threadIdx.x) * 16;
#pragma unroll
  for (int j = 0; j < 4; ++j) *(float4*)(op + j * 4) = z;
}

// ---------------- gemm2: uniform BM=64 tiles, 256 blocks.
// z<128:  U  = NLOG2E*(emb.w1^T)            (K=256)
// z>=128: QC = NLOG2E*(emb.w2^T + CE.w3^T + b3)  (K=512 over [emb|CE])
__global__ __launch_bounds__(256) void gemm2_k(
    const float* __restrict__ emb, const float* __restrict__ CE,
    const float* __restrict__ w1, const float* __restrict__ w2, const float* __restrict__ w3,
    const float* __restrict__ b3, float* __restrict__ U, float* __restrict__ QC) {
  __shared__ float As[64 * 32], Ws[64 * 32];
  const int tid = threadIdx.x, tx = tid & 15, ty = tid >> 4;
  const int z = blockIdx.x;
  const bool isU = z < 128;
  const int y = isU ? z : z - 128;
  const int r0 = (y >> 2) * 64, f0 = (y & 3) * 64;
  const int nk = isU ? 8 : 16;
  float acc[4][4] = {};
  for (int kb = 0; kb < nk; ++kb) {
    const float* A = isU ? emb : (kb < 8 ? emb : CE);
    const float* W = isU ? w1 : (kb < 8 ? w2 : w3);
    const int kk = (kb & 7) * 32;
    for (int j = 0; j < 2; ++j) {
      int idx = j * 256 + tid;
      int r = idx >> 3, g = idx & 7;
      int gs = g ^ ((r >> 2) & 7);
      *(float4*)(As + r * 32 + gs * 4) = *(const float4*)(A + (size_t)(r0 + r) * E_ + kk + g * 4);
      *(float4*)(Ws + r * 32 + gs * 4) = *(const float4*)(W + (size_t)(f0 + r) * E_ + kk + g * 4);
    }
    __syncthreads();
#pragma unroll
    for (int g = 0; g < 8; ++g) {
      float4 a[4], w[4];
#pragma unroll
      for (int i = 0; i < 4; ++i) {
        int r = ty * 4 + i;
        a[i] = *(const float4*)(As + r * 32 + (g ^ ((r >> 2) & 7)) * 4);
        int f = tx * 4 + i;
        w[i] = *(const float4*)(Ws + f * 32 + (g ^ ((f >> 2) & 7)) * 4);
      }
#pragma unroll
      for (int i = 0; i < 4; ++i)
#pragma unroll
        for (int j = 0; j < 4; ++j)
          acc[i][j] += a[i].x * w[j].x + a[i].y * w[j].y + a[i].z * w[j].z + a[i].w * w[j].w;
    }
    __syncthreads();
  }
  if (isU) {
#pragma unroll
    for (int i = 0; i < 4; ++i) {
      float4 v = make_float4(acc[i][0] * NLOG2E, acc[i][1] * NLOG2E,
                             acc[i][2] * NLOG2E, acc[i][3] * NLOG2E);
      *(float4*)(U + (size_t)(r0 + ty * 4 + i) * E_ + f0 + tx * 4) = v;
    }
  } else {
    float4 bb = *(const float4*)(b3 + f0 + tx * 4);
#pragma unroll
    for (int i = 0; i < 4; ++i) {
      float4 v = make_float4(NLOG2E * (acc[i][0] + bb.x), NLOG2E * (acc[i][1] + bb.y),
                             NLOG2E * (acc[i][2] + bb.z), NLOG2E * (acc[i][3] + bb.w));
      *(float4*)(QC + (size_t)(r0 + ty * 4 + i) * E_ + f0 + tx * 4) = v;
    }
  }
}

// ---------------- main: gate + PV for (t-tile of 16, i-chunk of 64, b); 8 waves,
// 2 wave-uniform t's per wave (scalar QC loads) — round-3 inner loop.
__global__ __launch_bounds__(512, 8) void attn_main_k(
    const float* __restrict__ emb, const float* __restrict__ U,
    const float* __restrict__ QC, const float* __restrict__ w0g,
    float* __restrict__ out) {
  const int t0 = blockIdx.x * TT, i0 = blockIdx.y * TI, b = blockIdx.z;
  if (i0 > t0) return;  // tile-aligned: inactive block

  __shared__ u16 tile[TI * 264];
  __shared__ float s_s[TT][TI];
  const int tid = threadIdx.x, wave = tid >> 6, lane = tid & 63;

  // stage U rows i0..i0+63 (bf16, pre-scaled by -log2e): wave w stages rows c*8+w
  {
    const float* src = U + ((size_t)i0 * B_ + b) * E_ + lane * 4;
#pragma unroll
    for (int c = 0; c < 8; ++c) {
      int r = c * 8 + wave;
      float4 v = *(const float4*)(src + (size_t)r * (B_ * E_));
      *(uint2*)(tile + r * 264 + lane * 4) =
          make_uint2(pack_bf2(v.x, v.y), pack_bf2(v.z, v.w));
    }
  }
  __syncthreads();

  const int tA = t0 + wave * 2, tB = tA + 1;
  {
    int rA = __builtin_amdgcn_readfirstlane(tA * B_ + b);
    int rB = __builtin_amdgcn_readfirstlane(tB * B_ + b);
    const float* qA = QC + (size_t)rA * E_;
    const float* qB = QC + (size_t)rB * E_;
    const u16* urow = tile + lane * 264;
    float a0 = 0.f, a1 = 0.f, a2 = 0.f, a3 = 0.f;
    float c0 = 0.f, c1 = 0.f, c2 = 0.f, c3 = 0.f;
#pragma unroll 4
    for (int g = 0; g < 32; ++g) {
      uint4 raw = *(const uint4*)(urow + g * 8);
      float4 z0 = *(const float4*)(w0g + g * 8);
      float4 z1 = *(const float4*)(w0g + g * 8 + 4);
      float4 qa0 = *(const float4*)(qA + g * 8);
      float4 qa1 = *(const float4*)(qA + g * 8 + 4);
      float4 qb0 = *(const float4*)(qB + g * 8);
      float4 qb1 = *(const float4*)(qB + g * 8 + 4);
      float u0 = bflo(raw.x), u1 = bfhi(raw.x), u2 = bflo(raw.y), u3 = bfhi(raw.y);
      float u4 = bflo(raw.z), u5 = bfhi(raw.z), u6 = bflo(raw.w), u7 = bfhi(raw.w);
      a0 += z0.x * sigs(u0 + qa0.x); a1 += z0.y * sigs(u1 + qa0.y);
      a2 += z0.z * sigs(u2 + qa0.z); a3 += z0.w * sigs(u3 + qa0.w);
      a0 += z1.x * sigs(u4 + qa1.x); a1 += z1.y * sigs(u5 + qa1.y);
      a2 += z1.z * sigs(u6 + qa1.z); a3 += z1.w * sigs(u7 + qa1.w);
      c0 += z0.x * sigs(u0 + qb0.x); c1 += z0.y * sigs(u1 + qb0.y);
      c2 += z0.z * sigs(u2 + qb0.z); c3 += z0.w * sigs(u3 + qb0.w);
      c0 += z1.x * sigs(u4 + qb1.x); c1 += z1.y * sigs(u5 + qb1.y);
      c2 += z1.z * sigs(u6 + qb1.z); c3 += z1.w * sigs(u7 + qb1.w);
    }
    float sA = (a0 + a1) + (a2 + a3), sB = (c0 + c1) + (c2 + c3);
    int i = i0 + lane;
    s_s[wave * 2][lane]     = (i <= tA) ? sA : 0.f;
    s_s[wave * 2 + 1][lane] = (i <= tB) ? sB : 0.f;
  }
  __syncthreads();

  // PV: per wave 2 t's; lanes own e (4 floats); emb direct from global (L1)
  {
    const float* embp = emb + ((size_t)i0 * B_ + b) * E_ + lane * 4;
    const float* sAv = s_s[wave * 2];
    const float* sBv = s_s[wave * 2 + 1];
    int nI = min(TI, tB - i0 + 1);
    nI = (nI + 3) & ~3;
    float4 o0 = {0.f, 0.f, 0.f, 0.f}, o1 = {0.f, 0.f, 0.f, 0.f};
    for (int i = 0; i < nI; i += 4) {
#pragma unroll
      for (int k2 = 0; k2 < 4; ++k2) {
        float4 r = *(const float4*)(embp + (size_t)(i + k2) * (B_ * E_));
        float sa = sAv[i + k2], sb = sBv[i + k2];
        o0.x += sa * r.x; o0.y += sa * r.y; o0.z += sa * r.z; o0.w += sa * r.w;
        o1.x += sb * r.x; o1.y += sb * r.y; o1.z += sb * r.z; o1.w += sb * r.w;
      }
    }
    float* opA = out + ((size_t)tA * B_ + b) * E_ + lane * 4;
    float* opB = out + ((size_t)tB * B_ + b) * E_ + lane * 4;
    atomicAdd(opA + 0, o0.x); atomicAdd(opA + 1, o0.y);
    atomicAdd(opA + 2, o0.z); atomicAdd(opA + 3, o0.w);
    atomicAdd(opB + 0, o1.x); atomicAdd(opB + 1, o1.y);
    atomicAdd(opB + 2, o1.z); atomicAdd(opB + 3, o1.w);
  }
}

extern "C" void kernel_launch(void* const* d_in, const int* in_sizes, int n_in,
                              void* d_out, int out_size, void* d_ws, size_t ws_size,
                              hipStream_t stream) {
  const float* emb = (const float*)d_in[0];
  const float* w1  = (const float*)d_in[1];
  const float* w2  = (const float*)d_in[2];
  const float* w3  = (const float*)d_in[3];
  const float* b3  = (const float*)d_in[4];
  const float* w0  = (const float*)d_in[5];
  float* out = (float*)d_out;

  float* CE = (float*)d_ws;            // 2048x256 cumsum(emb)
  float* U  = CE + 524288;             // 2048x256, pre-scaled by -log2e
  float* QC = U + 524288;              // 2048x256, NLOG2E*(q2+c3+b3)

  prescan_k<<<dim3(128), 256, 0, stream>>>(emb, CE, out);
  gemm2_k<<<dim3(256), 256, 0, stream>>>(emb, CE, w1, w2, w3, b3, U, QC);
  attn_main_k<<<dim3(L_ / TT, L_ / TI, B_), 512, 0, stream>>>(emb, U, QC, w0, out);
}

// Round 11
// 157.180 us; speedup vs baseline: 1.3014x; 1.1012x over previous
//
#include <hip/hip_runtime.h>
#include <hip/hip_bf16.h>
#include <hip/hip_cooperative_groups.h>

namespace cg = cooperative_groups;

#define L_  512
#define B_  4
#define E_  256

typedef unsigned short u16;
#define NLOG2E (-1.44269504f)

__device__ __forceinline__ float bflo(unsigned u) { return __uint_as_float(u << 16); }
__device__ __forceinline__ float bfhi(unsigned u) { return __uint_as_float(u & 0xffff0000u); }

__device__ __forceinline__ unsigned pack_bf2(float x, float y) {
  __hip_bfloat162 h = __float22bfloat162_rn(make_float2(x, y));
  return *reinterpret_cast<unsigned*>(&h);
}

// inputs pre-scaled by -log2(e):  sig(x) = 1/(1+2^(xs)) = sigmoid(original x)
__device__ __forceinline__ float sigs(float xs) {
  float e = __builtin_amdgcn_exp2f(xs);
  return __builtin_amdgcn_rcpf(1.0f + e);
}

// ================= cooperative fused kernel: grid-stride phases =================
__global__ __launch_bounds__(512, 2) void coop_k(
    const float* __restrict__ emb,
    const float* __restrict__ w1, const float* __restrict__ w2, const float* __restrict__ w3,
    const float* __restrict__ b3, const float* __restrict__ w0g,
    float* __restrict__ U, float* __restrict__ Q2, float* __restrict__ V3,
    float* __restrict__ out) {
  __shared__ union {
    struct { float As[2048], Wa[2048], Wb[2048]; } g;     // 24 KB (gemm)
    float4 sp[64][8];                                     // 8 KB  (scan)
    struct { u16 tile[64 * 264]; float ss[16][64]; } a;   // 37.9 KB (attn)
  } sm;

  cg::grid_group grid = cg::this_grid();
  const int tid = threadIdx.x, bid = blockIdx.x, nblk = gridDim.x;

  // ---------- phase 1: 256 gemm jobs (z<128: U = scl*emb.w1^T; z>=128: Q2=emb.w2^T, V3=emb.w3^T)
  for (int z = bid; z < 256; z += nblk) {
    const bool isU = z < 128;
    const int y = z & 127;
    const int r0 = (y >> 2) * 64, f0 = (y & 3) * 64;
    const int tx = tid & 15, ty = tid >> 4;   // 16 x 32
    float acc0[2][4] = {}, acc1[2][4] = {};
    for (int kb = 0; kb < 8; ++kb) {
      const int kk = kb * 32;
      {
        int r = tid >> 3, g = tid & 7;
        int gs = g ^ ((r >> 2) & 7);
        *(float4*)(sm.g.As + r * 32 + gs * 4) =
            *(const float4*)(emb + (size_t)(r0 + r) * E_ + kk + g * 4);
        const float* Wp = isU ? w1 : w2;
        *(float4*)(sm.g.Wa + r * 32 + gs * 4) =
            *(const float4*)(Wp + (size_t)(f0 + r) * E_ + kk + g * 4);
        if (!isU)
          *(float4*)(sm.g.Wb + r * 32 + gs * 4) =
              *(const float4*)(w3 + (size_t)(f0 + r) * E_ + kk + g * 4);
      }
      __syncthreads();
#pragma unroll
      for (int g = 0; g < 8; ++g) {
        float4 a[2], wa[4], wb[4];
#pragma unroll
        for (int i = 0; i < 2; ++i) {
          int r = ty * 2 + i;
          a[i] = *(const float4*)(sm.g.As + r * 32 + (g ^ ((r >> 2) & 7)) * 4);
        }
#pragma unroll
        for (int j = 0; j < 4; ++j) {
          int f = tx * 4 + j;
          int off = f * 32 + (g ^ ((f >> 2) & 7)) * 4;
          wa[j] = *(const float4*)(sm.g.Wa + off);
          if (!isU) wb[j] = *(const float4*)(sm.g.Wb + off);
        }
#pragma unroll
        for (int i = 0; i < 2; ++i)
#pragma unroll
          for (int j = 0; j < 4; ++j) {
            acc0[i][j] += a[i].x * wa[j].x + a[i].y * wa[j].y + a[i].z * wa[j].z + a[i].w * wa[j].w;
            if (!isU)
              acc1[i][j] += a[i].x * wb[j].x + a[i].y * wb[j].y + a[i].z * wb[j].z + a[i].w * wb[j].w;
          }
      }
      __syncthreads();
    }
    if (isU) {
#pragma unroll
      for (int i = 0; i < 2; ++i) {
        float4 v = make_float4(acc0[i][0] * NLOG2E, acc0[i][1] * NLOG2E,
                               acc0[i][2] * NLOG2E, acc0[i][3] * NLOG2E);
        *(float4*)(U + (size_t)(r0 + ty * 2 + i) * E_ + f0 + tx * 4) = v;
      }
    } else {
#pragma unroll
      for (int i = 0; i < 2; ++i) {
        size_t o = (size_t)(r0 + ty * 2 + i) * E_ + f0 + tx * 4;
        *(float4*)(Q2 + o) = make_float4(acc0[i][0], acc0[i][1], acc0[i][2], acc0[i][3]);
        *(float4*)(V3 + o) = make_float4(acc1[i][0], acc1[i][1], acc1[i][2], acc1[i][3]);
      }
    }
  }
  // zero-init out: 256 slices x 2048 floats
  for (int z = bid; z < 256; z += nblk) {
    const float4 z4 = {0.f, 0.f, 0.f, 0.f};
    *(float4*)(out + (size_t)z * 2048 + tid * 4) = z4;
  }

  grid.sync();

  // ---------- phase 2: scan jobs (32): QC = NLOG2E*(Q2 + b3 + prefix_incl(V3)), in-place in Q2
  for (int sb = bid; sb < 32; sb += nblk) {
    const int cgi = tid & 7, rk = tid >> 3;       // 8 f4-cols x 64 row-chunks
    const int c4 = sb * 8 + cgi;                  // float4 column in [0,256)
    const float* v3p = V3 + c4 * 4;
    float4 part = {0.f, 0.f, 0.f, 0.f};
    for (int l = rk * 8; l < rk * 8 + 8; ++l) {
      float4 v = *(const float4*)(v3p + (size_t)l * 1024);
      part.x += v.x; part.y += v.y; part.z += v.z; part.w += v.w;
    }
    sm.sp[rk][cgi] = part;
    __syncthreads();
    float4 run = {0.f, 0.f, 0.f, 0.f};
    for (int k = 0; k < rk; ++k) {
      float4 p = sm.sp[k][cgi];
      run.x += p.x; run.y += p.y; run.z += p.z; run.w += p.w;
    }
    float4 bb = *(const float4*)(b3 + (c4 & 63) * 4);
    float* q2p = Q2 + c4 * 4;
    for (int l = rk * 8; l < rk * 8 + 8; ++l) {
      size_t o = (size_t)l * 1024;
      float4 v = *(const float4*)(v3p + o);
      run.x += v.x; run.y += v.y; run.z += v.z; run.w += v.w;
      float4 q = *(const float4*)(q2p + o);
      float4 r;
      r.x = NLOG2E * (q.x + bb.x + run.x);
      r.y = NLOG2E * (q.y + bb.y + run.y);
      r.z = NLOG2E * (q.z + bb.z + run.z);
      r.w = NLOG2E * (q.w + bb.w + run.w);
      *(float4*)(q2p + o) = r;
    }
    __syncthreads();
  }

  grid.sync();

  // ---------- phase 3: gate + PV, grid-stride over 576 tiles (TT=16, TI=64)
  const int wave = tid >> 6, lane = tid & 63;
  for (int tile = bid; tile < 576; tile += nblk) {
    const int b = tile & 3;
    int j = tile >> 2;                     // [0,144)
    int tt = 0;
    while (true) { int c = (tt >> 2) + 1; if (j < c) break; j -= c; ++tt; }
    const int t0 = tt * 16, i0 = j * 64;

    __syncthreads();   // protect LDS reuse across iterations

    // stage U rows i0..i0+63 (bf16, pre-scaled): wave w stages rows c*8+w
    {
      const float* src = U + ((size_t)i0 * B_ + b) * E_ + lane * 4;
#pragma unroll
      for (int c = 0; c < 8; ++c) {
        int r = c * 8 + wave;
        float4 v = *(const float4*)(src + (size_t)r * (B_ * E_));
        *(uint2*)(sm.a.tile + r * 264 + lane * 4) =
            make_uint2(pack_bf2(v.x, v.y), pack_bf2(v.z, v.w));
      }
    }
    __syncthreads();

    const int tA = t0 + wave * 2, tB = tA + 1;
    {
      int rA = __builtin_amdgcn_readfirstlane(tA * B_ + b);
      int rB = __builtin_amdgcn_readfirstlane(tB * B_ + b);
      const float* qA = Q2 + (size_t)rA * E_;
      const float* qB = Q2 + (size_t)rB * E_;
      const u16* urow = sm.a.tile + lane * 264;
      float a0 = 0.f, a1 = 0.f, a2 = 0.f, a3 = 0.f;
      float c0 = 0.f, c1 = 0.f, c2 = 0.f, c3 = 0.f;
#pragma unroll 4
      for (int g = 0; g < 32; ++g) {
        uint4 raw = *(const uint4*)(urow + g * 8);
        float4 z0 = *(const float4*)(w0g + g * 8);
        float4 z1 = *(const float4*)(w0g + g * 8 + 4);
        float4 qa0 = *(const float4*)(qA + g * 8);
        float4 qa1 = *(const float4*)(qA + g * 8 + 4);
        float4 qb0 = *(const float4*)(qB + g * 8);
        float4 qb1 = *(const float4*)(qB + g * 8 + 4);
        float u0 = bflo(raw.x), u1 = bfhi(raw.x), u2 = bflo(raw.y), u3 = bfhi(raw.y);
        float u4 = bflo(raw.z), u5 = bfhi(raw.z), u6 = bflo(raw.w), u7 = bfhi(raw.w);
        a0 += z0.x * sigs(u0 + qa0.x); a1 += z0.y * sigs(u1 + qa0.y);
        a2 += z0.z * sigs(u2 + qa0.z); a3 += z0.w * sigs(u3 + qa0.w);
        a0 += z1.x * sigs(u4 + qa1.x); a1 += z1.y * sigs(u5 + qa1.y);
        a2 += z1.z * sigs(u6 + qa1.z); a3 += z1.w * sigs(u7 + qa1.w);
        c0 += z0.x * sigs(u0 + qb0.x); c1 += z0.y * sigs(u1 + qb0.y);
        c2 += z0.z * sigs(u2 + qb0.z); c3 += z0.w * sigs(u3 + qb0.w);
        c0 += z1.x * sigs(u4 + qb1.x); c1 += z1.y * sigs(u5 + qb1.y);
        c2 += z1.z * sigs(u6 + qb1.z); c3 += z1.w * sigs(u7 + qb1.w);
      }
      float sA = (a0 + a1) + (a2 + a3), sB = (c0 + c1) + (c2 + c3);
      int i = i0 + lane;
      sm.a.ss[wave * 2][lane]     = (i <= tA) ? sA : 0.f;
      sm.a.ss[wave * 2 + 1][lane] = (i <= tB) ? sB : 0.f;
    }
    __syncthreads();

    // PV
    {
      const float* embp = emb + ((size_t)i0 * B_ + b) * E_ + lane * 4;
      const float* sAv = sm.a.ss[wave * 2];
      const float* sBv = sm.a.ss[wave * 2 + 1];
      int nI = min(64, tB - i0 + 1);
      nI = (nI + 3) & ~3;
      float4 o0 = {0.f, 0.f, 0.f, 0.f}, o1 = {0.f, 0.f, 0.f, 0.f};
      for (int i = 0; i < nI; i += 4) {
#pragma unroll
        for (int k2 = 0; k2 < 4; ++k2) {
          float4 r = *(const float4*)(embp + (size_t)(i + k2) * (B_ * E_));
          float sa = sAv[i + k2], sb = sBv[i + k2];
          o0.x += sa * r.x; o0.y += sa * r.y; o0.z += sa * r.z; o0.w += sa * r.w;
          o1.x += sb * r.x; o1.y += sb * r.y; o1.z += sb * r.z; o1.w += sb * r.w;
        }
      }
      float* opA = out + ((size_t)tA * B_ + b) * E_ + lane * 4;
      float* opB = out + ((size_t)tB * B_ + b) * E_ + lane * 4;
      atomicAdd(opA + 0, o0.x); atomicAdd(opA + 1, o0.y);
      atomicAdd(opA + 2, o0.z); atomicAdd(opA + 3, o0.w);
      atomicAdd(opB + 0, o1.x); atomicAdd(opB + 1, o1.y);
      atomicAdd(opB + 2, o1.z); atomicAdd(opB + 3, o1.w);
    }
  }
}

// ================= fallback path (proven r7/r3 kernels) =================
__global__ __launch_bounds__(256) void prescan_k(
    const float* __restrict__ emb, float* __restrict__ CE, float* __restrict__ out0) {
  const int bc = blockIdx.x;
  const int cg = threadIdx.x & 1;
  const int rk = threadIdx.x >> 1;
  const int col = bc * 8 + cg * 4;
  __shared__ float4 s_p[128][2];
  float4 part = {0.f, 0.f, 0.f, 0.f};
  for (int l = rk * 4; l < rk * 4 + 4; ++l) {
    float4 v = *(const float4*)(emb + (size_t)l * 1024 + col);
    part.x += v.x; part.y += v.y; part.z += v.z; part.w += v.w;
  }
  s_p[rk][cg] = part;
  __syncthreads();
  float4 run = {0.f, 0.f, 0.f, 0.f};
  for (int k = 0; k < rk; ++k) {
    float4 p = s_p[k][cg];
    run.x += p.x; run.y += p.y; run.z += p.z; run.w += p.w;
  }
  for (int l = rk * 4; l < rk * 4 + 4; ++l) {
    size_t o = (size_t)l * 1024 + col;
    float4 v = *(const float4*)(emb + o);
    run.x += v.x; run.y += v.y; run.z += v.z; run.w += v.w;
    *(float4*)(CE + o) = run;
  }
  const float4 z = {0.f, 0.f, 0.f, 0.f};
  float* op = out0 + ((size_t)bc * 256 + threadIdx.x) * 16;
#pragma unroll
  for (int j = 0; j < 4; ++j) *(float4*)(op + j * 4) = z;
}

__global__ __launch_bounds__(256) void gemm2_k(
    const float* __restrict__ emb, const float* __restrict__ CE,
    const float* __restrict__ w1, const float* __restrict__ w2, const float* __restrict__ w3,
    const float* __restrict__ b3, float* __restrict__ U, float* __restrict__ QC) {
  __shared__ float As[64 * 32], Ws[64 * 32];
  const int tid = threadIdx.x, tx = tid & 15, ty = tid >> 4;
  const int z = blockIdx.x;
  const bool isU = z < 128;
  const int y = isU ? z : z - 128;
  const int r0 = (y >> 2) * 64, f0 = (y & 3) * 64;
  const int nk = isU ? 8 : 16;
  float acc[4][4] = {};
  for (int kb = 0; kb < nk; ++kb) {
    const float* A = isU ? emb : (kb < 8 ? emb : CE);
    const float* W = isU ? w1 : (kb < 8 ? w2 : w3);
    const int kk = (kb & 7) * 32;
    for (int j = 0; j < 2; ++j) {
      int idx = j * 256 + tid;
      int r = idx >> 3, g = idx & 7;
      int gs = g ^ ((r >> 2) & 7);
      *(float4*)(As + r * 32 + gs * 4) = *(const float4*)(A + (size_t)(r0 + r) * E_ + kk + g * 4);
      *(float4*)(Ws + r * 32 + gs * 4) = *(const float4*)(W + (size_t)(f0 + r) * E_ + kk + g * 4);
    }
    __syncthreads();
#pragma unroll
    for (int g = 0; g < 8; ++g) {
      float4 a[4], w[4];
#pragma unroll
      for (int i = 0; i < 4; ++i) {
        int r = ty * 4 + i;
        a[i] = *(const float4*)(As + r * 32 + (g ^ ((r >> 2) & 7)) * 4);
        int f = tx * 4 + i;
        w[i] = *(const float4*)(Ws + f * 32 + (g ^ ((f >> 2) & 7)) * 4);
      }
#pragma unroll
      for (int i = 0; i < 4; ++i)
#pragma unroll
        for (int j = 0; j < 4; ++j)
          acc[i][j] += a[i].x * w[j].x + a[i].y * w[j].y + a[i].z * w[j].z + a[i].w * w[j].w;
    }
    __syncthreads();
  }
  if (isU) {
#pragma unroll
    for (int i = 0; i < 4; ++i) {
      float4 v = make_float4(acc[i][0] * NLOG2E, acc[i][1] * NLOG2E,
                             acc[i][2] * NLOG2E, acc[i][3] * NLOG2E);
      *(float4*)(U + (size_t)(r0 + ty * 4 + i) * E_ + f0 + tx * 4) = v;
    }
  } else {
    float4 bb = *(const float4*)(b3 + f0 + tx * 4);
#pragma unroll
    for (int i = 0; i < 4; ++i) {
      float4 v = make_float4(NLOG2E * (acc[i][0] + bb.x), NLOG2E * (acc[i][1] + bb.y),
                             NLOG2E * (acc[i][2] + bb.z), NLOG2E * (acc[i][3] + bb.w));
      *(float4*)(QC + (size_t)(r0 + ty * 4 + i) * E_ + f0 + tx * 4) = v;
    }
  }
}

__global__ __launch_bounds__(256) void attn3_k(
    const float* __restrict__ emb, const float* __restrict__ U,
    const float* __restrict__ QC, const float* __restrict__ w0g,
    float* __restrict__ out) {
  const int t0 = blockIdx.x * 8, i0 = blockIdx.y * 64, b = blockIdx.z;
  if (i0 > t0) return;

  __shared__ u16 tile[64 * 264];
  __shared__ float s_s[8][64];
  const int tid = threadIdx.x, wave = tid >> 6, lane = tid & 63;

  {
    const float* src = U + ((size_t)i0 * B_ + b) * E_ + lane * 4;
#pragma unroll
    for (int c = 0; c < 16; ++c) {
      int r = c * 4 + wave;
      float4 v = *(const float4*)(src + (size_t)r * (B_ * E_));
      *(uint2*)(tile + r * 264 + lane * 4) =
          make_uint2(pack_bf2(v.x, v.y), pack_bf2(v.z, v.w));
    }
  }
  __syncthreads();

  const int tA = t0 + wave * 2, tB = tA + 1;
  {
    int rA = __builtin_amdgcn_readfirstlane(tA * B_ + b);
    int rB = __builtin_amdgcn_readfirstlane(tB * B_ + b);
    const float* qA = QC + (size_t)rA * E_;
    const float* qB = QC + (size_t)rB * E_;
    const u16* urow = tile + lane * 264;
    float a0 = 0.f, a1 = 0.f, a2 = 0.f, a3 = 0.f;
    float c0 = 0.f, c1 = 0.f, c2 = 0.f, c3 = 0.f;
#pragma unroll 4
    for (int g = 0; g < 32; ++g) {
      uint4 raw = *(const uint4*)(urow + g * 8);
      float4 z0 = *(const float4*)(w0g + g * 8);
      float4 z1 = *(const float4*)(w0g + g * 8 + 4);
      float4 qa0 = *(const float4*)(qA + g * 8);
      float4 qa1 = *(const float4*)(qA + g * 8 + 4);
      float4 qb0 = *(const float4*)(qB + g * 8);
      float4 qb1 = *(const float4*)(qB + g * 8 + 4);
      float u0 = bflo(raw.x), u1 = bfhi(raw.x), u2 = bflo(raw.y), u3 = bfhi(raw.y);
      float u4 = bflo(raw.z), u5 = bfhi(raw.z), u6 = bflo(raw.w), u7 = bfhi(raw.w);
      a0 += z0.x * sigs(u0 + qa0.x); a1 += z0.y * sigs(u1 + qa0.y);
      a2 += z0.z * sigs(u2 + qa0.z); a3 += z0.w * sigs(u3 + qa0.w);
      a0 += z1.x * sigs(u4 + qa1.x); a1 += z1.y * sigs(u5 + qa1.y);
      a2 += z1.z * sigs(u6 + qa1.z); a3 += z1.w * sigs(u7 + qa1.w);
      c0 += z0.x * sigs(u0 + qb0.x); c1 += z0.y * sigs(u1 + qb0.y);
      c2 += z0.z * sigs(u2 + qb0.z); c3 += z0.w * sigs(u3 + qb0.w);
      c0 += z1.x * sigs(u4 + qb1.x); c1 += z1.y * sigs(u5 + qb1.y);
      c2 += z1.z * sigs(u6 + qb1.z); c3 += z1.w * sigs(u7 + qb1.w);
    }
    float sA = (a0 + a1) + (a2 + a3), sB = (c0 + c1) + (c2 + c3);
    int i = i0 + lane;
    s_s[wave * 2][lane]     = (i <= tA) ? sA : 0.f;
    s_s[wave * 2 + 1][lane] = (i <= tB) ? sB : 0.f;
  }
  __syncthreads();

  {
    const float* embp = emb + ((size_t)i0 * B_ + b) * E_ + lane * 4;
    const float* sAv = s_s[wave * 2];
    const float* sBv = s_s[wave * 2 + 1];
    int nI = min(64, tB - i0 + 1);
    nI = (nI + 3) & ~3;
    float4 o0 = {0.f, 0.f, 0.f, 0.f}, o1 = {0.f, 0.f, 0.f, 0.f};
    for (int i = 0; i < nI; i += 4) {
#pragma unroll
      for (int k2 = 0; k2 < 4; ++k2) {
        float4 r = *(const float4*)(embp + (size_t)(i + k2) * (B_ * E_));
        float sa = sAv[i + k2], sb = sBv[i + k2];
        o0.x += sa * r.x; o0.y += sa * r.y; o0.z += sa * r.z; o0.w += sa * r.w;
        o1.x += sb * r.x; o1.y += sb * r.y; o1.z += sb * r.z; o1.w += sb * r.w;
      }
    }
    float* opA = out + ((size_t)tA * B_ + b) * E_ + lane * 4;
    float* opB = out + ((size_t)tB * B_ + b) * E_ + lane * 4;
    atomicAdd(opA + 0, o0.x); atomicAdd(opA + 1, o0.y);
    atomicAdd(opA + 2, o0.z); atomicAdd(opA + 3, o0.w);
    atomicAdd(opB + 0, o1.x); atomicAdd(opB + 1, o1.y);
    atomicAdd(opB + 2, o1.z); atomicAdd(opB + 3, o1.w);
  }
}

extern "C" void kernel_launch(void* const* d_in, const int* in_sizes, int n_in,
                              void* d_out, int out_size, void* d_ws, size_t ws_size,
                              hipStream_t stream) {
  const float* emb = (const float*)d_in[0];
  const float* w1  = (const float*)d_in[1];
  const float* w2  = (const float*)d_in[2];
  const float* w3  = (const float*)d_in[3];
  const float* b3  = (const float*)d_in[4];
  const float* w0  = (const float*)d_in[5];
  float* out = (float*)d_out;

  float* buf0 = (float*)d_ws;          // coop: U     | fallback: CE
  float* buf1 = buf0 + 524288;         // coop: Q2/QC | fallback: U
  float* buf2 = buf1 + 524288;         // coop: V3    | fallback: QC

  // deterministic host-side decision (device-static; same every call)
  int maxB = 0;
  hipError_t qe = hipOccupancyMaxActiveBlocksPerMultiprocessor(
      &maxB, (const void*)coop_k, 512, 0);
  if (qe == hipSuccess && maxB >= 1) {
    int g = maxB * 256;
    if (g > 512) g = 512;
    void* args[] = {(void*)&emb, (void*)&w1, (void*)&w2, (void*)&w3,
                    (void*)&b3, (void*)&w0, (void*)&buf0, (void*)&buf1,
                    (void*)&buf2, (void*)&out};
    hipError_t e = hipLaunchCooperativeKernel((const void*)coop_k, dim3(g),
                                              dim3(512), args, 0, stream);
    if (e == hipSuccess) return;
    (void)hipGetLastError();   // clear sticky error, fall through
  }

  // fallback: proven 3-kernel path
  prescan_k<<<dim3(128), 256, 0, stream>>>(emb, buf0, out);
  gemm2_k<<<dim3(256), 256, 0, stream>>>(emb, buf0, w1, w2, w3, b3, buf1, buf2);
  attn3_k<<<dim3(64, 8, 4), 256, 0, stream>>>(emb, buf1, buf2, w0, out);
}